// Round 7
// baseline (99.067 us; speedup 1.0000x reference)
//
#include <hip/hip_runtime.h>
#include <math.h>

#define NTOK 16384
#define DDIM 2048
#define NEXP 64
#define MT   128                 // tokens per stage-1 block
#define KSPLIT 8
#define KRANGE (DDIM / KSPLIT)   // 256
#define KC   32                  // k per LDS chunk (128 B rows)
#define NCH  (KRANGE / KC)       // 8

// ws layout (floats): [0..63] f counts, [64..127] P sums, [128] sum lse^2,
// [256 ...] partial logits: [KSPLIT][NTOK][NEXP]
#define PART_OFF 256

// x-tile LDS float index. One row = 32 floats = 128 B. A wave's xr read hits
// 4 rows stride-8 (rows ty*8+t, ty = 4w..4w+3): bits 3-4 of row take all 4
// values -> XOR col by ((row>>3)&3)*4 puts the 4 rows in 4 distinct bank
// quads. 16 lanes sharing a row broadcast (free).
#define XSWZ(row)      ((((row) >> 3) & 3) << 2)
#define XIDX(row, kf)  (((row) << 5) + ((kf) ^ XSWZ(row)))

__device__ __forceinline__ void gload16(const float* g, const float* lds) {
    __builtin_amdgcn_global_load_lds(
        (const __attribute__((address_space(1))) unsigned int*)g,
        (__attribute__((address_space(3))) unsigned int*)lds, 16, 0, 0);
}

__global__ void zero_acc(float* acc) {
    int t = threadIdx.x;
    if (t < 129) acc[t] = 0.0f;
}

__global__ __launch_bounds__(256, 3) void gemm_part(
    const float* __restrict__ x, const float* __restrict__ W,
    float* __restrict__ pws)
{
    __shared__ __align__(16) float xb[2][MT * KC];   // 2 x 16 KB, swizzled
    __shared__ __align__(16) float wb[2][KC * NEXP]; // 2 x 8 KB, linear

    const int tid  = threadIdx.x;
    const int tb   = blockIdx.x & (NTOK / MT - 1);  // token block 0..127
    const int s    = blockIdx.x >> 7;               // k-split 0..7
    const int tok0 = tb * MT;
    const int kb   = s * KRANGE;

    const int tx = tid & 15;             // experts 4tx..4tx+3
    const int ty = tid >> 4;             // tokens 8ty..8ty+7
    const int e0 = tx * 4;
    const int w  = tid >> 6;             // wave 0..3
    const int l  = tid & 63;             // lane

    // --- staging source addresses ---
    // x slot o = u*1024 + w*256 + l*4 : row = u*32 + w*8 + (l>>3),
    // lds col = (l&7)*4 ; global col = lds col ^ XSWZ(row).
    // (row>>3)&3 = (u*4 + w)&3 = w  -> swz = w<<2, u-invariant.
    const int xrow0 = w * 8 + (l >> 3);              // + u*32
    const int xcol  = ((l & 7) * 4) ^ (w << 2);
    const float* xsrc = x + (size_t)(tok0 + xrow0) * DDIM + kb + xcol;
    // W slot o = u*1024 + w*256 + l*4 : row = u*16 + w*4 + (l>>4), col=(l&15)*4
    const int wrow0 = w * 4 + (l >> 4);              // + u*16
    const int wcol  = (l & 15) * 4;
    const float* wsrc = W + (size_t)(kb + wrow0) * NEXP + wcol;

    float accv[8][4];
    #pragma unroll
    for (int t = 0; t < 8; ++t)
        #pragma unroll
        for (int j = 0; j < 4; ++j) accv[t][j] = 0.0f;

    // prologue: stage chunk 0 into buffer 0
    #pragma unroll
    for (int u = 0; u < 4; ++u)
        gload16(xsrc + (size_t)u * 32 * DDIM, &xb[0][u * 1024 + w * 256]);
    #pragma unroll
    for (int u = 0; u < 2; ++u)
        gload16(wsrc + (size_t)u * 16 * NEXP, &wb[0][u * 1024 + w * 256]);

    const int tr0 = ty * 8;              // first token row of this thread
    const int xsw = (ty & 3) << 2;       // XSWZ(tr0+t), t<8: loop-invariant

    for (int c = 0; c < NCH; ++c) {
        __syncthreads();   // drains vmcnt -> chunk c staged; prev compute done
        const int cur = c & 1;
        if (c + 1 < NCH) {
            const int nb = cur ^ 1;
            const int ko = (c + 1) * KC;
            #pragma unroll
            for (int u = 0; u < 4; ++u)
                gload16(xsrc + ko + (size_t)u * 32 * DDIM,
                        &xb[nb][u * 1024 + w * 256]);
            #pragma unroll
            for (int u = 0; u < 2; ++u)
                gload16(wsrc + (size_t)(ko + u * 16) * NEXP,
                        &wb[nb][u * 1024 + w * 256]);
        }
        const float* xcb = xb[cur];
        const float* wcb = wb[cur];
        #pragma unroll
        for (int s2 = 0; s2 < KC / 4; ++s2) {
            float wr[4][4];
            #pragma unroll
            for (int r = 0; r < 4; ++r)
                *(float4*)wr[r] = *(const float4*)&wcb[(4 * s2 + r) * NEXP + e0];
            #pragma unroll
            for (int t = 0; t < 8; ++t) {
                float xr[4];
                *(float4*)xr =
                    *(const float4*)&xcb[((tr0 + t) << 5) + ((4 * s2) ^ xsw)];
                #pragma unroll
                for (int r = 0; r < 4; ++r)      // k ascending per acc element
                    #pragma unroll
                    for (int j = 0; j < 4; ++j)
                        accv[t][j] = fmaf(xr[r], wr[r][j], accv[t][j]);
            }
        }
    }

    // store partial logits pws[s][tok][e], coalesced float4
    float* pb = pws + ((size_t)s * NTOK + tok0) * NEXP;
    #pragma unroll
    for (int t = 0; t < 8; ++t)
        *(float4*)&pb[(size_t)(tr0 + t) * NEXP + e0] = *(float4*)accv[t];
}

#define ETOK 64   // tokens per epilogue block

__global__ __launch_bounds__(256) void epilogue(
    const float* __restrict__ pws, const float* __restrict__ bias,
    float* __restrict__ out, float* __restrict__ acc_g)
{
    __shared__ int   f_loc[NEXP];
    __shared__ float p_loc[NEXP];
    __shared__ float z_loc;

    const int tid = threadIdx.x;
    const int tx  = tid & 15;         // expert group: 4tx..4tx+3
    const int tg  = tid >> 4;         // token slot 0..15
    const int e0  = tx * 4;

    if (tid < NEXP) { f_loc[tid] = 0; p_loc[tid] = 0.0f; }
    if (tid == 0) z_loc = 0.0f;
    __syncthreads();

    float bb[4];
    *(float4*)bb = *(const float4*)&bias[e0];

    float pacc[4] = {0.f, 0.f, 0.f, 0.f};
    float zacc = 0.0f;

    for (int it = 0; it < ETOK / 16; ++it) {
        const int gt = blockIdx.x * ETOK + it * 16 + tg;

        // sum 8 partials in fixed ascending-s order, then + bias
        float l[4];
        {
            const size_t ro = (size_t)gt * NEXP + e0;
            float4 q[KSPLIT];
            #pragma unroll
            for (int sp = 0; sp < KSPLIT; ++sp)
                q[sp] = *(const float4*)&pws[(size_t)sp * NTOK * NEXP + ro];
            float a0 = q[0].x, a1 = q[0].y, a2 = q[0].z, a3 = q[0].w;
            #pragma unroll
            for (int sp = 1; sp < KSPLIT; ++sp) {
                a0 += q[sp].x; a1 += q[sp].y; a2 += q[sp].z; a3 += q[sp].w;
            }
            l[0] = a0 + bb[0]; l[1] = a1 + bb[1];
            l[2] = a2 + bb[2]; l[3] = a3 + bb[3];
        }

        // local top-2 (stable: ascending e, strict >)
        float v1 = l[0], v2 = -INFINITY;
        int   i1 = e0,   i2 = 0x7fffffff;
        #pragma unroll
        for (int j = 1; j < 4; ++j) {
            float v = l[j]; int e = e0 + j;
            if (v > v1)      { v2 = v1; i2 = i1; v1 = v; i1 = e; }
            else if (v > v2) { v2 = v;  i2 = e; }
        }
        // merge across the 16 lanes of this token (value desc, idx asc)
        #pragma unroll
        for (int off = 1; off < 16; off <<= 1) {
            float o1 = __shfl_xor(v1, off, 16); int oi1 = __shfl_xor(i1, off, 16);
            float o2 = __shfl_xor(v2, off, 16); int oi2 = __shfl_xor(i2, off, 16);
            if (o1 > v1 || (o1 == v1 && oi1 < i1)) {
                float cs = v1; int ci = i1;
                v1 = o1; i1 = oi1;
                if (cs > o2 || (cs == o2 && ci < oi2)) { v2 = cs; i2 = ci;  }
                else                                   { v2 = o2; i2 = oi2; }
            } else {
                if (o1 > v2 || (o1 == v2 && oi1 < i2)) { v2 = o1; i2 = oi1; }
            }
        }
        const float mx = v1;

        float sden[4], dsum = 0.0f;
        #pragma unroll
        for (int j = 0; j < 4; ++j) { sden[j] = __expf(l[j] - mx); dsum += sden[j]; }
        #pragma unroll
        for (int off = 1; off < 16; off <<= 1) dsum += __shfl_xor(dsum, off, 16);
        const float inv = 1.0f / dsum;

        float zsum = 0.0f;
        #pragma unroll
        for (int j = 0; j < 4; ++j) {
            float pj = sden[j] * inv;
            pacc[j] += pj;
            zsum += __expf(pj);
        }
        #pragma unroll
        for (int off = 1; off < 16; off <<= 1) zsum += __shfl_xor(zsum, off, 16);

        if (tx == 0) {
            const float s2 = __expf(v2 - mx);      // s1 == 1
            const float ci = 1.0f / (1.0f + s2);
            out[2 * gt]     = (float)i1;
            out[2 * gt + 1] = (float)i2;
            out[2 * NTOK + 2 * gt]     = ci;
            out[2 * NTOK + 2 * gt + 1] = s2 * ci;
            atomicAdd(&f_loc[i1], 1);
            float lse = __logf(zsum);
            zacc += lse * lse;
        }
    }

    // z: wave-reduce (only tx==0 lanes carry nonzero), one LDS atomic per wave
    #pragma unroll
    for (int off = 1; off < 64; off <<= 1) zacc += __shfl_xor(zacc, off);
    if ((tid & 63) == 0) atomicAdd(&z_loc, zacc);

    // P: fold token-groups within wave, then LDS
    #pragma unroll
    for (int j = 0; j < 4; ++j) {
        pacc[j] += __shfl_xor(pacc[j], 16);
        pacc[j] += __shfl_xor(pacc[j], 32);
    }
    if ((tid & 63) < 16) {
        #pragma unroll
        for (int j = 0; j < 4; ++j) atomicAdd(&p_loc[e0 + j], pacc[j]);
    }

    __syncthreads();
    if (tid < NEXP) {
        atomicAdd(&acc_g[64 + tid], p_loc[tid]);
        if (f_loc[tid]) atomicAdd(&acc_g[tid], (float)f_loc[tid]);
    }
    if (tid == 0) atomicAdd(&acc_g[128], z_loc);
}

__global__ void gate_finalize(const float* __restrict__ acc, float* __restrict__ out) {
    int e = threadIdx.x;  // 64 threads
    float v = acc[e] * acc[64 + e];
    #pragma unroll
    for (int off = 32; off > 0; off >>= 1) v += __shfl_down(v, off);
    if (e == 0) {
        const float NT = (float)NTOK;
        out[2 * NTOK * 2]     = 0.01f * (v / (float)NEXP) / (NT * NT);
        out[2 * NTOK * 2 + 1] = 0.1f * acc[128] / NT;
    }
}

extern "C" void kernel_launch(void* const* d_in, const int* in_sizes, int n_in,
                              void* d_out, int out_size, void* d_ws, size_t ws_size,
                              hipStream_t stream) {
    const float* x    = (const float*)d_in[0];
    const float* W    = (const float*)d_in[1];
    const float* bias = (const float*)d_in[2];
    float* out = (float*)d_out;
    float* acc = (float*)d_ws;
    float* pws = acc + PART_OFF;

    zero_acc<<<1, 256, 0, stream>>>(acc);
    gemm_part<<<KSPLIT * (NTOK / MT), 256, 0, stream>>>(x, W, pws);
    epilogue<<<NTOK / ETOK, 256, 0, stream>>>(pws, bias, out, acc);
    gate_finalize<<<1, 64, 0, stream>>>(acc, out);
}